// Round 2
// baseline (396.670 us; speedup 1.0000x reference)
//
#include <hip/hip_runtime.h>
#include <hip/hip_bf16.h>
#include <stdint.h>

// ResonanceAttention on MI355X (gfx950).
// Pipeline: zero_ent -> gemm_nt_f32 (Q, K, Vt) -> flash_attn (+entropy) -> gemm_out.
// Vt = V transposed is produced directly by swapping GEMM operand roles (A=v_w, B=hs),
// so attention's PV matmul gets k-contiguous B fragments with no transpose pass.
// Blend loop folds to scale C=0.8509655 applied iff avg_entropy >= 0.2 (computed on device).
// Workspace: Q(8MB) K(8MB) Vt(8MB) O(8MB) ent(4B) = 32MB+4.
// R1 hardening: no hipMemsetAsync (zero kernel instead); ws_size guard -> clean
// zero-output failure instead of OOB fault if workspace is too small (diagnostic).

#define PRIME_SCALE 0.047245559126654356f  // 1/sqrt(7*64)
#define BLEND_C     0.85096556f            // closed form of the MAX_ITERS recurrence

typedef __attribute__((ext_vector_type(8))) short short8;
typedef __attribute__((ext_vector_type(4))) float f32x4;

__device__ __forceinline__ unsigned short f2bf(float x) {
    union { float f; unsigned int u; } v; v.f = x;
    unsigned int r = (v.u + 0x7fffu + ((v.u >> 16) & 1u)) >> 16;  // RNE
    return (unsigned short)r;
}

__global__ void zero_ent(float* p) { p[0] = 0.f; }

__global__ void zero_out_f32(float* p, int n) {
    int i = blockIdx.x * 256 + threadIdx.x;
    if (i < n) p[i] = 0.f;
}

// ---------------------------------------------------------------------------
// Generic NT GEMM, fp32 inputs -> bf16 output.  C[m][n] = (sum_k A[m][k]*B[n][k] + bias)*scale
// K fixed = 1024. BM=BN=128, BK=32, 256 threads (4 waves, 2x2 of 64x64).
// LDS rows padded to 40 bf16 (80B) so b128 frag reads are 16B-aligned & ~conflict-free.
// ---------------------------------------------------------------------------
__global__ __launch_bounds__(256) void gemm_nt_f32(
    const float* __restrict__ A, const float* __restrict__ B,
    const float* __restrict__ bias, int biasRow, float scale,
    unsigned short* __restrict__ C, int N)
{
    const int m0 = blockIdx.x * 128;
    const int n0 = blockIdx.y * 128;
    __shared__ unsigned short As[128 * 40];
    __shared__ unsigned short Bs[128 * 40];
    const int t = threadIdx.x;
    const int lane = t & 63;
    const int w = t >> 6;
    const int wr = (w >> 1) * 64;
    const int wc = (w & 1) * 64;
    const int quad = lane >> 4, l15 = lane & 15;

    f32x4 acc[4][4];
#pragma unroll
    for (int i = 0; i < 4; ++i)
#pragma unroll
        for (int j = 0; j < 4; ++j) acc[i][j] = (f32x4){0.f, 0.f, 0.f, 0.f};

    for (int kk = 0; kk < 32; ++kk) {
        const int k0 = kk * 32;
#pragma unroll
        for (int i = 0; i < 4; ++i) {
            int f = i * 256 + t;
            int row = f >> 3, ch = f & 7;
            float4 av = *(const float4*)&A[(size_t)(m0 + row) * 1024 + k0 + ch * 4];
            ushort4 ap; ap.x = f2bf(av.x); ap.y = f2bf(av.y); ap.z = f2bf(av.z); ap.w = f2bf(av.w);
            *(ushort4*)&As[row * 40 + ch * 4] = ap;
            float4 bv = *(const float4*)&B[(size_t)(n0 + row) * 1024 + k0 + ch * 4];
            ushort4 bp; bp.x = f2bf(bv.x); bp.y = f2bf(bv.y); bp.z = f2bf(bv.z); bp.w = f2bf(bv.w);
            *(ushort4*)&Bs[row * 40 + ch * 4] = bp;
        }
        __syncthreads();
        short8 af[4], bfr[4];
#pragma unroll
        for (int mt = 0; mt < 4; ++mt)
            af[mt] = *(const short8*)&As[(wr + mt * 16 + l15) * 40 + quad * 8];
#pragma unroll
        for (int nt = 0; nt < 4; ++nt)
            bfr[nt] = *(const short8*)&Bs[(wc + nt * 16 + l15) * 40 + quad * 8];
#pragma unroll
        for (int mt = 0; mt < 4; ++mt)
#pragma unroll
            for (int nt = 0; nt < 4; ++nt)
                acc[mt][nt] = __builtin_amdgcn_mfma_f32_16x16x32_bf16(af[mt], bfr[nt], acc[mt][nt], 0, 0, 0);
        __syncthreads();
    }
    // epilogue: C row = quad*4+reg, col = lane&15  [m89/m91-verified C/D layout]
#pragma unroll
    for (int mt = 0; mt < 4; ++mt) {
#pragma unroll
        for (int nt = 0; nt < 4; ++nt) {
            int n = n0 + wc + nt * 16 + l15;
#pragma unroll
            for (int r = 0; r < 4; ++r) {
                int m = m0 + wr + mt * 16 + quad * 4 + r;
                float bval = biasRow ? bias[m] : bias[n];
                float v = (acc[mt][nt][r] + bval) * scale;  // ref: (x@W.T + b) * scale
                C[(size_t)m * N + n] = f2bf(v);
            }
        }
    }
}

// ---------------------------------------------------------------------------
// Flash attention per (b,h) with 64-row Q tiles; online softmax + entropy.
// Q,K: [4096][1024] bf16 (Q pre-scaled by PRIME_SCALE). Vt: [1024][4096] bf16.
// O: [4096][1024] bf16 merged layout. entp: scalar entropy-sum accumulator.
// 256 threads = 4 waves; wave w owns q-rows w*16..w*16+15 of the tile.
// ---------------------------------------------------------------------------
__global__ __launch_bounds__(256) void flash_attn(
    const unsigned short* __restrict__ Q,
    const unsigned short* __restrict__ K,
    const unsigned short* __restrict__ Vt,
    const int* __restrict__ mask,
    unsigned short* __restrict__ O,
    float* __restrict__ entp)
{
    const int qt = blockIdx.x;          // 0..31 q-tile
    const int bh = blockIdx.y;          // 0..31
    const int b = bh >> 4, h = bh & 15;
    const int t = threadIdx.x, lane = t & 63, w = t >> 6;
    const int quad = lane >> 4, l15 = lane & 15;

    __shared__ unsigned short Qs[64 * 72];  // rows=q, cols=d   (72 = 64+8 pad, 144B stride)
    __shared__ unsigned short Ks[64 * 72];  // rows=k, cols=d
    __shared__ unsigned short Vs[64 * 72];  // rows=d, cols=k  (from Vt, no transpose needed)
    __shared__ unsigned short Ps[64 * 72];  // rows=q, cols=k  (softmax probs, per-wave region)

    // stage Q tile once
#pragma unroll
    for (int i = 0; i < 2; ++i) {
        int f = i * 256 + t; int row = f >> 3, ch = f & 7;
        uint4 v = *(const uint4*)&Q[(size_t)(b * 2048 + qt * 64 + row) * 1024 + h * 64 + ch * 8];
        *(uint4*)&Qs[row * 72 + ch * 8] = v;
    }

    float m_r[4], l_r[4], T_r[4];
    f32x4 o_acc[4];
#pragma unroll
    for (int r = 0; r < 4; ++r) { m_r[r] = -3.0e38f; l_r[r] = 0.f; T_r[r] = 0.f; }
#pragma unroll
    for (int nt = 0; nt < 4; ++nt) o_acc[nt] = (f32x4){0.f, 0.f, 0.f, 0.f};

    const int* maskb = mask + b * 2048;

    for (int kt = 0; kt < 32; ++kt) {
#pragma unroll
        for (int i = 0; i < 2; ++i) {
            int f = i * 256 + t; int row = f >> 3, ch = f & 7;
            uint4 kv = *(const uint4*)&K[(size_t)(b * 2048 + kt * 64 + row) * 1024 + h * 64 + ch * 8];
            *(uint4*)&Ks[row * 72 + ch * 8] = kv;
            uint4 vv = *(const uint4*)&Vt[(size_t)(h * 64 + row) * 4096 + b * 2048 + kt * 64 + ch * 8];
            *(uint4*)&Vs[row * 72 + ch * 8] = vv;
        }
        __syncthreads();

        // S = Q K^T  (16 q-rows x 64 k-cols per wave)
        f32x4 sacc[4];
#pragma unroll
        for (int nt = 0; nt < 4; ++nt) sacc[nt] = (f32x4){0.f, 0.f, 0.f, 0.f};
        short8 qa0 = *(const short8*)&Qs[(w * 16 + l15) * 72 + quad * 8];
        short8 qa1 = *(const short8*)&Qs[(w * 16 + l15) * 72 + 32 + quad * 8];
#pragma unroll
        for (int nt = 0; nt < 4; ++nt) {
            short8 kf0 = *(const short8*)&Ks[(nt * 16 + l15) * 72 + quad * 8];
            short8 kf1 = *(const short8*)&Ks[(nt * 16 + l15) * 72 + 32 + quad * 8];
            sacc[nt] = __builtin_amdgcn_mfma_f32_16x16x32_bf16(qa0, kf0, sacc[nt], 0, 0, 0);
            sacc[nt] = __builtin_amdgcn_mfma_f32_16x16x32_bf16(qa1, kf1, sacc[nt], 0, 0, 0);
        }
        int mk[4];
#pragma unroll
        for (int nt = 0; nt < 4; ++nt) mk[nt] = maskb[kt * 64 + nt * 16 + l15];

        // online softmax + entropy partials, rows = quad*4+r
#pragma unroll
        for (int r = 0; r < 4; ++r) {
            float s0 = mk[0] ? sacc[0][r] : -1.0e30f;
            float s1 = mk[1] ? sacc[1][r] : -1.0e30f;
            float s2 = mk[2] ? sacc[2][r] : -1.0e30f;
            float s3 = mk[3] ? sacc[3][r] : -1.0e30f;
            float mx = fmaxf(fmaxf(s0, s1), fmaxf(s2, s3));
            mx = fmaxf(mx, __shfl_xor(mx, 1));
            mx = fmaxf(mx, __shfl_xor(mx, 2));
            mx = fmaxf(mx, __shfl_xor(mx, 4));
            mx = fmaxf(mx, __shfl_xor(mx, 8));
            float mnew = fmaxf(m_r[r], mx);
            float al = __expf(m_r[r] - mnew);
            float d0 = s0 - mnew, d1 = s1 - mnew, d2 = s2 - mnew, d3 = s3 - mnew;
            float p0 = __expf(d0), p1 = __expf(d1), p2 = __expf(d2), p3 = __expf(d3);
            float lp = p0 + p1 + p2 + p3;
            float tp = p0 * d0 + p1 * d1 + p2 * d2 + p3 * d3;  // sum p*(s-m) for entropy
            l_r[r] = l_r[r] * al + lp;
            T_r[r] = T_r[r] * al + tp;
            m_r[r] = mnew;
#pragma unroll
            for (int nt = 0; nt < 4; ++nt) o_acc[nt][r] *= al;
            int pbase = (w * 16 + quad * 4 + r) * 72 + l15;
            Ps[pbase]      = f2bf(p0);
            Ps[pbase + 16] = f2bf(p1);
            Ps[pbase + 32] = f2bf(p2);
            Ps[pbase + 48] = f2bf(p3);
        }

        // O += P V  (Ps per-wave region: no cross-wave barrier needed)
#pragma unroll
        for (int ks = 0; ks < 2; ++ks) {
            short8 pa = *(const short8*)&Ps[(w * 16 + l15) * 72 + ks * 32 + quad * 8];
#pragma unroll
            for (int nt = 0; nt < 4; ++nt) {
                short8 vf = *(const short8*)&Vs[(nt * 16 + l15) * 72 + ks * 32 + quad * 8];
                o_acc[nt] = __builtin_amdgcn_mfma_f32_16x16x32_bf16(pa, vf, o_acc[nt], 0, 0, 0);
            }
        }
        __syncthreads();
    }

    // finalize: row sums across the 16 lanes of each quad, write O, entropy
    float entacc = 0.f;
#pragma unroll
    for (int r = 0; r < 4; ++r) {
        float l = l_r[r], T = T_r[r];
        l += __shfl_xor(l, 1); T += __shfl_xor(T, 1);
        l += __shfl_xor(l, 2); T += __shfl_xor(T, 2);
        l += __shfl_xor(l, 4); T += __shfl_xor(T, 4);
        l += __shfl_xor(l, 8); T += __shfl_xor(T, 8);
        float inv = 1.0f / l;
        float ent = __logf(l) - T * inv;   // -sum p log p
        if (l15 == 0) entacc += ent;
        int mrow = b * 2048 + qt * 64 + w * 16 + quad * 4 + r;
#pragma unroll
        for (int nt = 0; nt < 4; ++nt)
            O[(size_t)mrow * 1024 + h * 64 + nt * 16 + l15] = f2bf(o_acc[nt][r] * inv);
    }
    entacc += __shfl_xor(entacc, 1);
    entacc += __shfl_xor(entacc, 2);
    entacc += __shfl_xor(entacc, 4);
    entacc += __shfl_xor(entacc, 8);
    entacc += __shfl_xor(entacc, 16);
    entacc += __shfl_xor(entacc, 32);
    if (lane == 0) atomicAdd(entp, entacc);
}

// ---------------------------------------------------------------------------
// Output GEMM: out[m][n] = scale_ent * sum_k O_bf16[m][k]*o_w[n][k] + o_b[n], fp32 out.
// scale_ent decided from the device-side entropy sum (avg >= 0.2 -> BLEND_C).
// ---------------------------------------------------------------------------
__global__ __launch_bounds__(256) void gemm_out(
    const unsigned short* __restrict__ A, const float* __restrict__ B,
    const float* __restrict__ bias, const float* __restrict__ entp,
    float* __restrict__ C)
{
    const float avg = entp[0] * (1.0f / 65536.0f);      // mean over B*H*S rows
    const float scale = (avg < 0.2f) ? 1.0f : BLEND_C;  // ref's where(avg_entropy<thresh,...)

    const int m0 = blockIdx.x * 128;
    const int n0 = blockIdx.y * 128;
    __shared__ unsigned short As[128 * 40];
    __shared__ unsigned short Bs[128 * 40];
    const int t = threadIdx.x;
    const int lane = t & 63;
    const int w = t >> 6;
    const int wr = (w >> 1) * 64;
    const int wc = (w & 1) * 64;
    const int quad = lane >> 4, l15 = lane & 15;

    f32x4 acc[4][4];
#pragma unroll
    for (int i = 0; i < 4; ++i)
#pragma unroll
        for (int j = 0; j < 4; ++j) acc[i][j] = (f32x4){0.f, 0.f, 0.f, 0.f};

    for (int kk = 0; kk < 32; ++kk) {
        const int k0 = kk * 32;
#pragma unroll
        for (int i = 0; i < 2; ++i) {          // A is bf16: 512 x 16B chunks
            int f = i * 256 + t;
            int row = f >> 2, ch = f & 3;
            uint4 av = *(const uint4*)&A[(size_t)(m0 + row) * 1024 + k0 + ch * 8];
            *(uint4*)&As[row * 40 + ch * 8] = av;
        }
#pragma unroll
        for (int i = 0; i < 4; ++i) {          // B is fp32: convert while staging
            int f = i * 256 + t;
            int row = f >> 3, ch = f & 7;
            float4 bv = *(const float4*)&B[(size_t)(n0 + row) * 1024 + k0 + ch * 4];
            ushort4 bp; bp.x = f2bf(bv.x); bp.y = f2bf(bv.y); bp.z = f2bf(bv.z); bp.w = f2bf(bv.w);
            *(ushort4*)&Bs[row * 40 + ch * 4] = bp;
        }
        __syncthreads();
        short8 af[4], bfr[4];
#pragma unroll
        for (int mt = 0; mt < 4; ++mt)
            af[mt] = *(const short8*)&As[(wr + mt * 16 + l15) * 40 + quad * 8];
#pragma unroll
        for (int nt = 0; nt < 4; ++nt)
            bfr[nt] = *(const short8*)&Bs[(wc + nt * 16 + l15) * 40 + quad * 8];
#pragma unroll
        for (int mt = 0; mt < 4; ++mt)
#pragma unroll
            for (int nt = 0; nt < 4; ++nt)
                acc[mt][nt] = __builtin_amdgcn_mfma_f32_16x16x32_bf16(af[mt], bfr[nt], acc[mt][nt], 0, 0, 0);
        __syncthreads();
    }
#pragma unroll
    for (int mt = 0; mt < 4; ++mt) {
#pragma unroll
        for (int nt = 0; nt < 4; ++nt) {
            int n = n0 + wc + nt * 16 + l15;
#pragma unroll
            for (int r = 0; r < 4; ++r) {
                int m = m0 + wr + mt * 16 + quad * 4 + r;
                C[(size_t)m * 1024 + n] = scale * acc[mt][nt][r] + bias[n];  // scale*base@W.T + b
            }
        }
    }
}

extern "C" void kernel_launch(void* const* d_in, const int* in_sizes, int n_in,
                              void* d_out, int out_size, void* d_ws, size_t ws_size,
                              hipStream_t stream)
{
    const float* hs = (const float*)d_in[0];
    const float* qw = (const float*)d_in[1];
    const float* qb = (const float*)d_in[2];
    const float* kw = (const float*)d_in[3];
    const float* kb = (const float*)d_in[4];
    const float* vw = (const float*)d_in[5];
    const float* vb = (const float*)d_in[6];
    const float* ow = (const float*)d_in[7];
    const float* ob = (const float*)d_in[8];
    const int*   mask = (const int*)d_in[9];
    float* out = (float*)d_out;

    const size_t NEED = (size_t)32 * 1024 * 1024 + 4;
    if (ws_size < NEED) {
        // Diagnostic fallback: clean zero output instead of OOB container fault.
        zero_out_f32<<<dim3((out_size + 255) / 256), dim3(256), 0, stream>>>(out, out_size);
        return;
    }

    char* ws = (char*)d_ws;
    unsigned short* Q  = (unsigned short*)(ws);
    unsigned short* Kp = (unsigned short*)(ws + (size_t)8  * 1024 * 1024);
    unsigned short* Vt = (unsigned short*)(ws + (size_t)16 * 1024 * 1024);
    unsigned short* O  = (unsigned short*)(ws + (size_t)24 * 1024 * 1024);
    float* entp        = (float*)(ws + (size_t)32 * 1024 * 1024);

    dim3 blk(256);
    zero_ent<<<dim3(1), dim3(1), 0, stream>>>(entp);
    // Q = (hs@qw.T + qb)*PRIME_SCALE  -> [4096][1024]
    gemm_nt_f32<<<dim3(32, 8), blk, 0, stream>>>(hs, qw, qb, 0, PRIME_SCALE, Q, 1024);
    // K = hs@kw.T + kb                -> [4096][1024]
    gemm_nt_f32<<<dim3(32, 8), blk, 0, stream>>>(hs, kw, kb, 0, 1.0f, Kp, 1024);
    // Vt = (hs@vw.T + vb)^T : swap operand roles -> [1024][4096], row-indexed bias
    gemm_nt_f32<<<dim3(8, 32), blk, 0, stream>>>(vw, hs, vb, 1, 1.0f, Vt, 4096);
    // attention + entropy
    flash_attn<<<dim3(32, 32), blk, 0, stream>>>(Q, Kp, Vt, mask, O, entp);
    // out = scale_ent*(O@ow.T) + ob
    gemm_out<<<dim3(32, 8), blk, 0, stream>>>(O, ow, ob, entp, out);
}

// Round 3
// 342.493 us; speedup vs baseline: 1.1582x; 1.1582x over previous
//
#include <hip/hip_runtime.h>
#include <hip/hip_bf16.h>
#include <stdint.h>

// ResonanceAttention on MI355X (gfx950) — round 3.
// Primary path (ws >= 40MB+4):
//   cvt5 (fp32->bf16 for hs + 4 weights, zeros entp) ->
//   gemm_qkv (fused Q/K/Vt, bf16 in, global_load_lds staging, 768 blocks) ->
//   flash_attn (no-max softmax, XOR-swizzled K/V LDS, reg prefetch, Ps aliases Qs) ->
//   gemm_out_bf (bf16 GEMM, 128x64 tiles, entropy-gated scale, fp32 out)
// Fallback path (32MB+4 <= ws < 40MB+4): round-2 fp32-staged GEMMs + new flash.
// Vt produced by swapping GEMM operand roles => PV matmul needs no transpose.
// Blend loop folds to scale C=0.8509655 iff avg_entropy >= 0.2 (device-computed).

#define PRIME_SCALE 0.047245559126654356f  // 1/sqrt(7*64)
#define BLEND_C     0.85096556f            // closed form of the MAX_ITERS recurrence

typedef __attribute__((ext_vector_type(8))) short short8;
typedef __attribute__((ext_vector_type(4))) float f32x4;

__device__ __forceinline__ unsigned short f2bf(float x) {
    union { float f; unsigned int u; } v; v.f = x;
    unsigned int r = (v.u + 0x7fffu + ((v.u >> 16) & 1u)) >> 16;  // RNE
    return (unsigned short)r;
}

// async global->LDS, 16B per lane; LDS dest = wave-uniform base + lane*16 [m97]
__device__ __forceinline__ void glds16(const unsigned short* g, unsigned short* l) {
    __builtin_amdgcn_global_load_lds((const __attribute__((address_space(1))) unsigned int*)g,
                                     (__attribute__((address_space(3))) unsigned int*)l,
                                     16, 0, 0);
}

__global__ void zero_ent(float* p) { p[0] = 0.f; }

__global__ void zero_out_f32(float* p, int n) {
    int i = blockIdx.x * 256 + threadIdx.x;
    if (i < n) p[i] = 0.f;
}

// ---------------------------------------------------------------------------
// cvt5: fp32 -> bf16 for hs (4M elems) + qw/kw/vw/ow (1M each). Zeros entp.
// ---------------------------------------------------------------------------
__global__ __launch_bounds__(256) void cvt5(
    const float* __restrict__ s0, const float* __restrict__ s1, const float* __restrict__ s2,
    const float* __restrict__ s3, const float* __restrict__ s4,
    unsigned short* __restrict__ d0, unsigned short* __restrict__ d1, unsigned short* __restrict__ d2,
    unsigned short* __restrict__ d3, unsigned short* __restrict__ d4, float* entp)
{
    if (blockIdx.x == 0 && threadIdx.x == 0) entp[0] = 0.f;
    unsigned int i = blockIdx.x * 256 + threadIdx.x;   // float4 group index, total 2^21
    const float* s; unsigned short* d; unsigned int off;
    if (i < (1u << 20)) { s = s0; d = d0; off = i; }
    else {
        unsigned int j = i - (1u << 20);
        unsigned int sel = j >> 18; off = j & 0x3FFFFu;
        s = sel == 0 ? s1 : sel == 1 ? s2 : sel == 2 ? s3 : s4;
        d = sel == 0 ? d1 : sel == 1 ? d2 : sel == 2 ? d3 : d4;
    }
    float4 v = ((const float4*)s)[off];
    ushort4 p; p.x = f2bf(v.x); p.y = f2bf(v.y); p.z = f2bf(v.z); p.w = f2bf(v.w);
    ((ushort4*)d)[off] = p;
}

// ---------------------------------------------------------------------------
// Fused Q/K/Vt GEMM, bf16 in -> bf16 out, global_load_lds staging (m97 structure).
// 768 blocks: op0=Q (hs@qw.T+qb)*PS, op1=K, op2=Vt (vw as A, hs as B -> transposed V).
// 128x128 tile, BK=32, K=1024 for all operands.
// ---------------------------------------------------------------------------
__global__ __launch_bounds__(256) void gemm_qkv(
    const unsigned short* __restrict__ hsb,
    const unsigned short* __restrict__ qwb, const unsigned short* __restrict__ kwb,
    const unsigned short* __restrict__ vwb,
    const float* __restrict__ qb, const float* __restrict__ kb, const float* __restrict__ vb,
    unsigned short* __restrict__ Qo, unsigned short* __restrict__ Ko, unsigned short* __restrict__ Vto)
{
    const int bid = blockIdx.x;
    const int op = bid >> 8, local = bid & 255;
    const unsigned short *A, *B; const float* bias; unsigned short* C;
    int m0, n0, ldc, biasRow; float scale;
    if (op == 0)      { A = hsb; B = qwb; bias = qb; C = Qo;  m0 = (local >> 3) * 128; n0 = (local & 7) * 128;  ldc = 1024; biasRow = 0; scale = PRIME_SCALE; }
    else if (op == 1) { A = hsb; B = kwb; bias = kb; C = Ko;  m0 = (local >> 3) * 128; n0 = (local & 7) * 128;  ldc = 1024; biasRow = 0; scale = 1.f; }
    else              { A = vwb; B = hsb; bias = vb; C = Vto; m0 = (local >> 5) * 128; n0 = (local & 31) * 128; ldc = 4096; biasRow = 1; scale = 1.f; }

    __shared__ unsigned short As[128 * 32];
    __shared__ unsigned short Bs[128 * 32];
    const int t = threadIdx.x, lane = t & 63, w = t >> 6;
    const int quad = lane >> 4, l15 = lane & 15;
    const int wr = (w >> 1) * 64, wc = (w & 1) * 64;
    const int srow = lane >> 2, scol = (lane & 3) * 8;   // lane's 16B chunk within a 16-row slab

    f32x4 acc[4][4];
#pragma unroll
    for (int i = 0; i < 4; ++i)
#pragma unroll
        for (int j = 0; j < 4; ++j) acc[i][j] = (f32x4){0.f, 0.f, 0.f, 0.f};

    for (int kk = 0; kk < 32; ++kk) {
        const int k0 = kk * 32;
#pragma unroll
        for (int j = 0; j < 2; ++j) {
            int row = (w * 2 + j) * 16 + srow;
            glds16(&A[(size_t)(m0 + row) * 1024 + k0 + scol], &As[(w * 2 + j) * 512]);
            glds16(&B[(size_t)(n0 + row) * 1024 + k0 + scol], &Bs[(w * 2 + j) * 512]);
        }
        __syncthreads();
        short8 af[4], bf[4];
#pragma unroll
        for (int mt = 0; mt < 4; ++mt) af[mt] = *(const short8*)&As[(wr + mt * 16 + l15) * 32 + quad * 8];
#pragma unroll
        for (int nt = 0; nt < 4; ++nt) bf[nt] = *(const short8*)&Bs[(wc + nt * 16 + l15) * 32 + quad * 8];
#pragma unroll
        for (int mt = 0; mt < 4; ++mt)
#pragma unroll
            for (int nt = 0; nt < 4; ++nt)
                acc[mt][nt] = __builtin_amdgcn_mfma_f32_16x16x32_bf16(af[mt], bf[nt], acc[mt][nt], 0, 0, 0);
        __syncthreads();
    }
#pragma unroll
    for (int mt = 0; mt < 4; ++mt) {
#pragma unroll
        for (int nt = 0; nt < 4; ++nt) {
            int n = n0 + wc + nt * 16 + l15;
#pragma unroll
            for (int r = 0; r < 4; ++r) {
                int m = m0 + wr + mt * 16 + quad * 4 + r;
                float bval = biasRow ? bias[m] : bias[n];
                C[(size_t)m * ldc + n] = f2bf((acc[mt][nt][r] + bval) * scale);
            }
        }
    }
}

// ---------------------------------------------------------------------------
// Flash attention, round-3: no-max softmax (scores |s|<~1 by construction; fixed
// m=0 is mathematically identical), XOR-swizzled K/V staging (stride 80, 2-way),
// register prefetch of next tile, Ps aliases Qs (Q frags hoisted pre-loop).
// Entropy: ent = log(l) - T/l, T = sum e^s * s.
// ---------------------------------------------------------------------------
__global__ __launch_bounds__(256) void flash_attn(
    const unsigned short* __restrict__ Q,
    const unsigned short* __restrict__ K,
    const unsigned short* __restrict__ Vt,
    const int* __restrict__ mask,
    unsigned short* __restrict__ O,
    float* __restrict__ entp)
{
    const int qt = blockIdx.x;          // 0..31 q-tile
    const int bh = blockIdx.y;          // 0..31
    const int b = bh >> 4, h = bh & 15;
    const int t = threadIdx.x, lane = t & 63, w = t >> 6;
    const int quad = lane >> 4, l15 = lane & 15;

    __shared__ unsigned short Qs[64 * 72];  // Q staged once; reused as Ps after frag hoist
    __shared__ unsigned short Ks[64 * 80];  // rows=k, cols=d; chunk ^= row&7 (2-way banks)
    __shared__ unsigned short Vs[64 * 80];  // rows=d, cols=k; same swizzle

    // stage Q tile (once; stride-72 plain — one-time cost)
#pragma unroll
    for (int i = 0; i < 2; ++i) {
        int f = i * 256 + t; int row = f >> 3, ch = f & 7;
        uint4 v = *(const uint4*)&Q[(size_t)(b * 2048 + qt * 64 + row) * 1024 + h * 64 + ch * 8];
        *(uint4*)&Qs[row * 72 + ch * 8] = v;
    }
    __syncthreads();
    const short8 qa0 = *(const short8*)&Qs[(w * 16 + l15) * 72 + quad * 8];
    const short8 qa1 = *(const short8*)&Qs[(w * 16 + l15) * 72 + 32 + quad * 8];
    unsigned short* Ps = Qs;  // safe: all waves re-sync before first Ps write

    float l_r[4], T_r[4];
    f32x4 o_acc[4];
#pragma unroll
    for (int r = 0; r < 4; ++r) { l_r[r] = 0.f; T_r[r] = 0.f; }
#pragma unroll
    for (int nt = 0; nt < 4; ++nt) o_acc[nt] = (f32x4){0.f, 0.f, 0.f, 0.f};

    const int* maskb = mask + b * 2048;
    const int srow = t >> 3;          // staging row within 32-row slab (per i)
    const int sch = t & 7;            // staging chunk

    // prefetch tile 0
    uint4 kreg[2], vreg[2];
#pragma unroll
    for (int i = 0; i < 2; ++i) {
        int row = i * 32 + srow;
        kreg[i] = *(const uint4*)&K[(size_t)(b * 2048 + row) * 1024 + h * 64 + sch * 8];
        vreg[i] = *(const uint4*)&Vt[(size_t)(h * 64 + row) * 4096 + b * 2048 + sch * 8];
    }

    for (int kt = 0; kt < 32; ++kt) {
        __syncthreads();   // prev tile's LDS reads done (also drains our prefetch loads)
#pragma unroll
        for (int i = 0; i < 2; ++i) {
            int row = i * 32 + srow;
            int eff = (sch ^ (row & 7)) * 8;
            *(uint4*)&Ks[row * 80 + eff] = kreg[i];
            *(uint4*)&Vs[row * 80 + eff] = vreg[i];
        }
        __syncthreads();   // stores visible
        if (kt < 31) {     // issue next tile's loads now — in flight during compute
            int kn = (kt + 1) * 64;
#pragma unroll
            for (int i = 0; i < 2; ++i) {
                int row = i * 32 + srow;
                kreg[i] = *(const uint4*)&K[(size_t)(b * 2048 + kn + row) * 1024 + h * 64 + sch * 8];
                vreg[i] = *(const uint4*)&Vt[(size_t)(h * 64 + row) * 4096 + b * 2048 + kn + sch * 8];
            }
        }

        // S = Q K^T (16 q-rows x 64 k-cols per wave)
        f32x4 sacc[4];
#pragma unroll
        for (int nt = 0; nt < 4; ++nt) sacc[nt] = (f32x4){0.f, 0.f, 0.f, 0.f};
#pragma unroll
        for (int nt = 0; nt < 4; ++nt) {
            int krow = nt * 16 + l15;
            short8 kf0 = *(const short8*)&Ks[krow * 80 + ((quad) ^ (l15 & 7)) * 8];
            short8 kf1 = *(const short8*)&Ks[krow * 80 + ((quad + 4) ^ (l15 & 7)) * 8];
            sacc[nt] = __builtin_amdgcn_mfma_f32_16x16x32_bf16(qa0, kf0, sacc[nt], 0, 0, 0);
            sacc[nt] = __builtin_amdgcn_mfma_f32_16x16x32_bf16(qa1, kf1, sacc[nt], 0, 0, 0);
        }
        int mk[4];
#pragma unroll
        for (int nt = 0; nt < 4; ++nt) mk[nt] = maskb[kt * 64 + nt * 16 + l15];

        // no-max softmax partials + P store (rows = w*16 + quad*4 + r)
#pragma unroll
        for (int r = 0; r < 4; ++r) {
            float s0 = mk[0] ? sacc[0][r] : -1.0e30f;
            float s1 = mk[1] ? sacc[1][r] : -1.0e30f;
            float s2 = mk[2] ? sacc[2][r] : -1.0e30f;
            float s3 = mk[3] ? sacc[3][r] : -1.0e30f;
            float p0 = __expf(s0), p1 = __expf(s1), p2 = __expf(s2), p3 = __expf(s3);
            l_r[r] += (p0 + p1) + (p2 + p3);
            T_r[r] += (p0 * s0 + p1 * s1) + (p2 * s2 + p3 * s3);
            int pbase = (w * 16 + quad * 4 + r) * 72 + l15;
            Ps[pbase]      = f2bf(p0);
            Ps[pbase + 16] = f2bf(p1);
            Ps[pbase + 32] = f2bf(p2);
            Ps[pbase + 48] = f2bf(p3);
        }

        // O += P V  (Ps rows are per-wave: no cross-wave barrier needed)
#pragma unroll
        for (int ks = 0; ks < 2; ++ks) {
            short8 pa = *(const short8*)&Ps[(w * 16 + l15) * 72 + ks * 32 + quad * 8];
#pragma unroll
            for (int nt = 0; nt < 4; ++nt) {
                int vrow = nt * 16 + l15;
                short8 vf = *(const short8*)&Vs[vrow * 80 + ((ks * 4 + quad) ^ (l15 & 7)) * 8];
                o_acc[nt] = __builtin_amdgcn_mfma_f32_16x16x32_bf16(pa, vf, o_acc[nt], 0, 0, 0);
            }
        }
    }

    // finalize: reduce l,T across the 16 lanes of each quad; write O; entropy
    float entacc = 0.f;
#pragma unroll
    for (int r = 0; r < 4; ++r) {
        float l = l_r[r], T = T_r[r];
        l += __shfl_xor(l, 1); T += __shfl_xor(T, 1);
        l += __shfl_xor(l, 2); T += __shfl_xor(T, 2);
        l += __shfl_xor(l, 4); T += __shfl_xor(T, 4);
        l += __shfl_xor(l, 8); T += __shfl_xor(T, 8);
        float inv = 1.0f / l;
        float ent = __logf(l) - T * inv;   // -sum p log p
        if (l15 == 0) entacc += ent;
        int mrow = b * 2048 + qt * 64 + w * 16 + quad * 4 + r;
#pragma unroll
        for (int nt = 0; nt < 4; ++nt)
            O[(size_t)mrow * 1024 + h * 64 + nt * 16 + l15] = f2bf(o_acc[nt][r] * inv);
    }
    entacc += __shfl_xor(entacc, 1);
    entacc += __shfl_xor(entacc, 2);
    entacc += __shfl_xor(entacc, 4);
    entacc += __shfl_xor(entacc, 8);
    entacc += __shfl_xor(entacc, 16);
    entacc += __shfl_xor(entacc, 32);
    if (lane == 0) atomicAdd(entp, entacc);
}

// ---------------------------------------------------------------------------
// Output GEMM bf16: out = scale_ent * (O @ ow.T) + ob, fp32 out.
// 128x64 tiles -> 512 blocks (2/CU). global_load_lds staging.
// ---------------------------------------------------------------------------
__global__ __launch_bounds__(256) void gemm_out_bf(
    const unsigned short* __restrict__ A, const unsigned short* __restrict__ Bw,
    const float* __restrict__ bias, const float* __restrict__ entp,
    float* __restrict__ C)
{
    const float avg = entp[0] * (1.0f / 65536.0f);
    const float scale = (avg < 0.2f) ? 1.0f : BLEND_C;

    const int m0 = blockIdx.x * 128;
    const int n0 = blockIdx.y * 64;
    __shared__ unsigned short As[128 * 32];
    __shared__ unsigned short Bs[64 * 32];
    const int t = threadIdx.x, lane = t & 63, w = t >> 6;
    const int quad = lane >> 4, l15 = lane & 15;
    const int wr = (w >> 1) * 64, wc = (w & 1) * 32;
    const int srow = lane >> 2, scol = (lane & 3) * 8;

    f32x4 acc[4][2];
#pragma unroll
    for (int i = 0; i < 4; ++i)
#pragma unroll
        for (int j = 0; j < 2; ++j) acc[i][j] = (f32x4){0.f, 0.f, 0.f, 0.f};

    for (int kk = 0; kk < 32; ++kk) {
        const int k0 = kk * 32;
#pragma unroll
        for (int j = 0; j < 2; ++j) {
            int row = (w * 2 + j) * 16 + srow;
            glds16(&A[(size_t)(m0 + row) * 1024 + k0 + scol], &As[(w * 2 + j) * 512]);
        }
        {
            int row = w * 16 + srow;
            glds16(&Bw[(size_t)(n0 + row) * 1024 + k0 + scol], &Bs[w * 512]);
        }
        __syncthreads();
        short8 af[4], bf[2];
#pragma unroll
        for (int mt = 0; mt < 4; ++mt) af[mt] = *(const short8*)&As[(wr + mt * 16 + l15) * 32 + quad * 8];
#pragma unroll
        for (int nt = 0; nt < 2; ++nt) bf[nt] = *(const short8*)&Bs[(wc + nt * 16 + l15) * 32 + quad * 8];
#pragma unroll
        for (int mt = 0; mt < 4; ++mt)
#pragma unroll
            for (int nt = 0; nt < 2; ++nt)
                acc[mt][nt] = __builtin_amdgcn_mfma_f32_16x16x32_bf16(af[mt], bf[nt], acc[mt][nt], 0, 0, 0);
        __syncthreads();
    }
#pragma unroll
    for (int mt = 0; mt < 4; ++mt) {
#pragma unroll
        for (int nt = 0; nt < 2; ++nt) {
            int n = n0 + wc + nt * 16 + l15;
#pragma unroll
            for (int r = 0; r < 4; ++r) {
                int m = m0 + wr + mt * 16 + quad * 4 + r;
                C[(size_t)m * 1024 + n] = scale * acc[mt][nt][r] + bias[n];
            }
        }
    }
}

// ---------------------------------------------------------------------------
// Fallback kernels (round-2 proven): fp32-staged GEMMs.
// ---------------------------------------------------------------------------
__global__ __launch_bounds__(256) void gemm_nt_f32(
    const float* __restrict__ A, const float* __restrict__ B,
    const float* __restrict__ bias, int biasRow, float scale,
    unsigned short* __restrict__ C, int N)
{
    const int m0 = blockIdx.x * 128;
    const int n0 = blockIdx.y * 128;
    __shared__ unsigned short As[128 * 40];
    __shared__ unsigned short Bs[128 * 40];
    const int t = threadIdx.x, lane = t & 63, w = t >> 6;
    const int wr = (w >> 1) * 64, wc = (w & 1) * 64;
    const int quad = lane >> 4, l15 = lane & 15;

    f32x4 acc[4][4];
#pragma unroll
    for (int i = 0; i < 4; ++i)
#pragma unroll
        for (int j = 0; j < 4; ++j) acc[i][j] = (f32x4){0.f, 0.f, 0.f, 0.f};

    for (int kk = 0; kk < 32; ++kk) {
        const int k0 = kk * 32;
#pragma unroll
        for (int i = 0; i < 4; ++i) {
            int f = i * 256 + t;
            int row = f >> 3, ch = f & 7;
            float4 av = *(const float4*)&A[(size_t)(m0 + row) * 1024 + k0 + ch * 4];
            ushort4 ap; ap.x = f2bf(av.x); ap.y = f2bf(av.y); ap.z = f2bf(av.z); ap.w = f2bf(av.w);
            *(ushort4*)&As[row * 40 + ch * 4] = ap;
            float4 bv = *(const float4*)&B[(size_t)(n0 + row) * 1024 + k0 + ch * 4];
            ushort4 bp; bp.x = f2bf(bv.x); bp.y = f2bf(bv.y); bp.z = f2bf(bv.z); bp.w = f2bf(bv.w);
            *(ushort4*)&Bs[row * 40 + ch * 4] = bp;
        }
        __syncthreads();
        short8 af[4], bfr[4];
#pragma unroll
        for (int mt = 0; mt < 4; ++mt) af[mt] = *(const short8*)&As[(wr + mt * 16 + l15) * 40 + quad * 8];
#pragma unroll
        for (int nt = 0; nt < 4; ++nt) bfr[nt] = *(const short8*)&Bs[(wc + nt * 16 + l15) * 40 + quad * 8];
#pragma unroll
        for (int mt = 0; mt < 4; ++mt)
#pragma unroll
            for (int nt = 0; nt < 4; ++nt)
                acc[mt][nt] = __builtin_amdgcn_mfma_f32_16x16x32_bf16(af[mt], bfr[nt], acc[mt][nt], 0, 0, 0);
        __syncthreads();
    }
#pragma unroll
    for (int mt = 0; mt < 4; ++mt) {
#pragma unroll
        for (int nt = 0; nt < 4; ++nt) {
            int n = n0 + wc + nt * 16 + l15;
#pragma unroll
            for (int r = 0; r < 4; ++r) {
                int m = m0 + wr + mt * 16 + quad * 4 + r;
                float bval = biasRow ? bias[m] : bias[n];
                C[(size_t)m * N + n] = f2bf((acc[mt][nt][r] + bval) * scale);
            }
        }
    }
}

__global__ __launch_bounds__(256) void gemm_out_f32B(
    const unsigned short* __restrict__ A, const float* __restrict__ B,
    const float* __restrict__ bias, const float* __restrict__ entp,
    float* __restrict__ C)
{
    const float avg = entp[0] * (1.0f / 65536.0f);
    const float scale = (avg < 0.2f) ? 1.0f : BLEND_C;

    const int m0 = blockIdx.x * 128;
    const int n0 = blockIdx.y * 128;
    __shared__ unsigned short As[128 * 40];
    __shared__ unsigned short Bs[128 * 40];
    const int t = threadIdx.x, lane = t & 63, w = t >> 6;
    const int wr = (w >> 1) * 64, wc = (w & 1) * 64;
    const int quad = lane >> 4, l15 = lane & 15;

    f32x4 acc[4][4];
#pragma unroll
    for (int i = 0; i < 4; ++i)
#pragma unroll
        for (int j = 0; j < 4; ++j) acc[i][j] = (f32x4){0.f, 0.f, 0.f, 0.f};

    for (int kk = 0; kk < 32; ++kk) {
        const int k0 = kk * 32;
#pragma unroll
        for (int i = 0; i < 2; ++i) {
            int f = i * 256 + t;
            int row = f >> 2, ch = f & 3;
            uint4 av = *(const uint4*)&A[(size_t)(m0 + row) * 1024 + k0 + ch * 8];
            *(uint4*)&As[row * 40 + ch * 8] = av;
        }
#pragma unroll
        for (int i = 0; i < 4; ++i) {
            int f = i * 256 + t;
            int row = f >> 3, ch = f & 7;
            float4 bv = *(const float4*)&B[(size_t)(n0 + row) * 1024 + k0 + ch * 4];
            ushort4 bp; bp.x = f2bf(bv.x); bp.y = f2bf(bv.y); bp.z = f2bf(bv.z); bp.w = f2bf(bv.w);
            *(ushort4*)&Bs[row * 40 + ch * 4] = bp;
        }
        __syncthreads();
        short8 af[4], bfr[4];
#pragma unroll
        for (int mt = 0; mt < 4; ++mt) af[mt] = *(const short8*)&As[(wr + mt * 16 + l15) * 40 + quad * 8];
#pragma unroll
        for (int nt = 0; nt < 4; ++nt) bfr[nt] = *(const short8*)&Bs[(wc + nt * 16 + l15) * 40 + quad * 8];
#pragma unroll
        for (int mt = 0; mt < 4; ++mt)
#pragma unroll
            for (int nt = 0; nt < 4; ++nt)
                acc[mt][nt] = __builtin_amdgcn_mfma_f32_16x16x32_bf16(af[mt], bfr[nt], acc[mt][nt], 0, 0, 0);
        __syncthreads();
    }
#pragma unroll
    for (int mt = 0; mt < 4; ++mt) {
#pragma unroll
        for (int nt = 0; nt < 4; ++nt) {
            int n = n0 + wc + nt * 16 + l15;
#pragma unroll
            for (int r = 0; r < 4; ++r) {
                int m = m0 + wr + mt * 16 + quad * 4 + r;
                C[(size_t)m * 1024 + n] = scale * acc[mt][nt][r] + bias[n];
            }
        }
    }
}

extern "C" void kernel_launch(void* const* d_in, const int* in_sizes, int n_in,
                              void* d_out, int out_size, void* d_ws, size_t ws_size,
                              hipStream_t stream)
{
    const float* hs = (const float*)d_in[0];
    const float* qw = (const float*)d_in[1];
    const float* qb = (const float*)d_in[2];
    const float* kw = (const float*)d_in[3];
    const float* kb = (const float*)d_in[4];
    const float* vw = (const float*)d_in[5];
    const float* vb = (const float*)d_in[6];
    const float* ow = (const float*)d_in[7];
    const float* ob = (const float*)d_in[8];
    const int*   mask = (const int*)d_in[9];
    float* out = (float*)d_out;

    const size_t MB = 1024 * 1024;
    char* ws = (char*)d_ws;
    dim3 blk(256);

    if (ws_size >= 40 * MB + 4) {
        // primary path
        unsigned short* hsb = (unsigned short*)(ws);            // 8MB; reused as O by flash
        unsigned short* Q   = (unsigned short*)(ws + 8 * MB);
        unsigned short* Kp  = (unsigned short*)(ws + 16 * MB);
        unsigned short* Vt  = (unsigned short*)(ws + 24 * MB);
        unsigned short* qwb = (unsigned short*)(ws + 32 * MB);
        unsigned short* kwb = (unsigned short*)(ws + 34 * MB);
        unsigned short* vwb = (unsigned short*)(ws + 36 * MB);
        unsigned short* owb = (unsigned short*)(ws + 38 * MB);
        float* entp         = (float*)(ws + 40 * MB);
        unsigned short* O   = hsb;  // hs_bf dead after gemm_qkv

        cvt5<<<dim3(8192), blk, 0, stream>>>(hs, qw, kw, vw, ow, hsb, qwb, kwb, vwb, owb, entp);
        gemm_qkv<<<dim3(768), blk, 0, stream>>>(hsb, qwb, kwb, vwb, qb, kb, vb, Q, Kp, Vt);
        flash_attn<<<dim3(32, 32), blk, 0, stream>>>(Q, Kp, Vt, mask, O, entp);
        gemm_out_bf<<<dim3(32, 16), blk, 0, stream>>>(O, owb, ob, entp, out);
    } else if (ws_size >= 32 * MB + 4) {
        // fallback: round-2 proven GEMMs + new flash
        unsigned short* Q  = (unsigned short*)(ws);
        unsigned short* Kp = (unsigned short*)(ws + 8 * MB);
        unsigned short* Vt = (unsigned short*)(ws + 16 * MB);
        unsigned short* O  = (unsigned short*)(ws + 24 * MB);
        float* entp        = (float*)(ws + 32 * MB);

        zero_ent<<<dim3(1), dim3(1), 0, stream>>>(entp);
        gemm_nt_f32<<<dim3(32, 8), blk, 0, stream>>>(hs, qw, qb, 0, PRIME_SCALE, Q, 1024);
        gemm_nt_f32<<<dim3(32, 8), blk, 0, stream>>>(hs, kw, kb, 0, 1.0f, Kp, 1024);
        gemm_nt_f32<<<dim3(8, 32), blk, 0, stream>>>(vw, hs, vb, 1, 1.0f, Vt, 4096);
        flash_attn<<<dim3(32, 32), blk, 0, stream>>>(Q, Kp, Vt, mask, O, entp);
        gemm_out_f32B<<<dim3(32, 8), blk, 0, stream>>>(O, ow, ob, entp, out);
    } else {
        // diagnostic: clean zero output instead of OOB fault
        zero_out_f32<<<dim3((out_size + 255) / 256), blk, 0, stream>>>(out, out_size);
    }
}

// Round 4
// 239.703 us; speedup vs baseline: 1.6548x; 1.4288x over previous
//
#include <hip/hip_runtime.h>
#include <hip/hip_bf16.h>
#include <stdint.h>

// ResonanceAttention on MI355X (gfx950) — round 4.
// R3 post-mortem: register-prefetch flash spilled to scratch (WRITE_SIZE 417MB).
// R4 flash: global_load_lds staging (no VGPR round-trip -> no spill), global-side
// XOR swizzle (LDS dest is wave-uniform; swizzle the *global* chunk instead),
// double-buffered K/V with ONE barrier per tile (DMA overlaps compute),
// 32 q-rows per wave (K/V frags shared across 2 subtiles), launch_bounds(256,2).
// Pipeline: cvt5 -> gemm_qkv (fused Q/K/Vt) -> flash_attn -> gemm_out_bf.
// Blend loop folds to scale C=0.8509655 iff avg_entropy >= 0.2 (device-computed).

#define PRIME_SCALE 0.047245559126654356f  // 1/sqrt(7*64)
#define BLEND_C     0.85096556f            // closed form of the MAX_ITERS recurrence

typedef __attribute__((ext_vector_type(8))) short short8;
typedef __attribute__((ext_vector_type(4))) float f32x4;

__device__ __forceinline__ unsigned short f2bf(float x) {
    union { float f; unsigned int u; } v; v.f = x;
    unsigned int r = (v.u + 0x7fffu + ((v.u >> 16) & 1u)) >> 16;  // RNE
    return (unsigned short)r;
}

// async global->LDS, 16B per lane; LDS dest = wave-uniform base + lane*16 [m97]
__device__ __forceinline__ void glds16(const unsigned short* g, unsigned short* l) {
    __builtin_amdgcn_global_load_lds((const __attribute__((address_space(1))) unsigned int*)g,
                                     (__attribute__((address_space(3))) unsigned int*)l,
                                     16, 0, 0);
}

__global__ void zero_ent(float* p) { p[0] = 0.f; }

__global__ void zero_out_f32(float* p, int n) {
    int i = blockIdx.x * 256 + threadIdx.x;
    if (i < n) p[i] = 0.f;
}

// ---------------------------------------------------------------------------
// cvt5: fp32 -> bf16 for hs (4M elems) + qw/kw/vw/ow (1M each). Zeros entp.
// ---------------------------------------------------------------------------
__global__ __launch_bounds__(256) void cvt5(
    const float* __restrict__ s0, const float* __restrict__ s1, const float* __restrict__ s2,
    const float* __restrict__ s3, const float* __restrict__ s4,
    unsigned short* __restrict__ d0, unsigned short* __restrict__ d1, unsigned short* __restrict__ d2,
    unsigned short* __restrict__ d3, unsigned short* __restrict__ d4, float* entp)
{
    if (blockIdx.x == 0 && threadIdx.x == 0) entp[0] = 0.f;
    unsigned int i = blockIdx.x * 256 + threadIdx.x;   // float4 group index, total 2^21
    const float* s; unsigned short* d; unsigned int off;
    if (i < (1u << 20)) { s = s0; d = d0; off = i; }
    else {
        unsigned int j = i - (1u << 20);
        unsigned int sel = j >> 18; off = j & 0x3FFFFu;
        s = sel == 0 ? s1 : sel == 1 ? s2 : sel == 2 ? s3 : s4;
        d = sel == 0 ? d1 : sel == 1 ? d2 : sel == 2 ? d3 : d4;
    }
    float4 v = ((const float4*)s)[off];
    ushort4 p; p.x = f2bf(v.x); p.y = f2bf(v.y); p.z = f2bf(v.z); p.w = f2bf(v.w);
    ((ushort4*)d)[off] = p;
}

// ---------------------------------------------------------------------------
// Fused Q/K/Vt GEMM, bf16 in -> bf16 out, global_load_lds staging (m97 structure).
// 768 blocks: op0=Q (hs@qw.T+qb)*PS, op1=K, op2=Vt (vw as A, hs as B -> transposed V).
// ---------------------------------------------------------------------------
__global__ __launch_bounds__(256) void gemm_qkv(
    const unsigned short* __restrict__ hsb,
    const unsigned short* __restrict__ qwb, const unsigned short* __restrict__ kwb,
    const unsigned short* __restrict__ vwb,
    const float* __restrict__ qb, const float* __restrict__ kb, const float* __restrict__ vb,
    unsigned short* __restrict__ Qo, unsigned short* __restrict__ Ko, unsigned short* __restrict__ Vto)
{
    const int bid = blockIdx.x;
    const int op = bid >> 8, local = bid & 255;
    const unsigned short *A, *B; const float* bias; unsigned short* C;
    int m0, n0, ldc, biasRow; float scale;
    if (op == 0)      { A = hsb; B = qwb; bias = qb; C = Qo;  m0 = (local >> 3) * 128; n0 = (local & 7) * 128;  ldc = 1024; biasRow = 0; scale = PRIME_SCALE; }
    else if (op == 1) { A = hsb; B = kwb; bias = kb; C = Ko;  m0 = (local >> 3) * 128; n0 = (local & 7) * 128;  ldc = 1024; biasRow = 0; scale = 1.f; }
    else              { A = vwb; B = hsb; bias = vb; C = Vto; m0 = (local >> 5) * 128; n0 = (local & 31) * 128; ldc = 4096; biasRow = 1; scale = 1.f; }

    __shared__ unsigned short As[128 * 32];
    __shared__ unsigned short Bs[128 * 32];
    const int t = threadIdx.x, lane = t & 63, w = t >> 6;
    const int quad = lane >> 4, l15 = lane & 15;
    const int wr = (w >> 1) * 64, wc = (w & 1) * 64;
    const int srow = lane >> 2, scol = (lane & 3) * 8;

    f32x4 acc[4][4];
#pragma unroll
    for (int i = 0; i < 4; ++i)
#pragma unroll
        for (int j = 0; j < 4; ++j) acc[i][j] = (f32x4){0.f, 0.f, 0.f, 0.f};

    for (int kk = 0; kk < 32; ++kk) {
        const int k0 = kk * 32;
#pragma unroll
        for (int j = 0; j < 2; ++j) {
            int row = (w * 2 + j) * 16 + srow;
            glds16(&A[(size_t)(m0 + row) * 1024 + k0 + scol], &As[(w * 2 + j) * 512]);
            glds16(&B[(size_t)(n0 + row) * 1024 + k0 + scol], &Bs[(w * 2 + j) * 512]);
        }
        __syncthreads();
        short8 af[4], bf[4];
#pragma unroll
        for (int mt = 0; mt < 4; ++mt) af[mt] = *(const short8*)&As[(wr + mt * 16 + l15) * 32 + quad * 8];
#pragma unroll
        for (int nt = 0; nt < 4; ++nt) bf[nt] = *(const short8*)&Bs[(wc + nt * 16 + l15) * 32 + quad * 8];
#pragma unroll
        for (int mt = 0; mt < 4; ++mt)
#pragma unroll
            for (int nt = 0; nt < 4; ++nt)
                acc[mt][nt] = __builtin_amdgcn_mfma_f32_16x16x32_bf16(af[mt], bf[nt], acc[mt][nt], 0, 0, 0);
        __syncthreads();
    }
#pragma unroll
    for (int mt = 0; mt < 4; ++mt) {
#pragma unroll
        for (int nt = 0; nt < 4; ++nt) {
            int n = n0 + wc + nt * 16 + l15;
#pragma unroll
            for (int r = 0; r < 4; ++r) {
                int m = m0 + wr + mt * 16 + quad * 4 + r;
                float bval = biasRow ? bias[m] : bias[n];
                C[(size_t)m * ldc + n] = f2bf((acc[mt][nt][r] + bval) * scale);
            }
        }
    }
}

// ---------------------------------------------------------------------------
// Flash attention r4: 128 q-rows/block (32/wave, 2 subtiles), glds16 K/V staging
// with global-side XOR swizzle, double-buffered LDS, ONE barrier per k-tile.
// No-max softmax (|s| <~ 1 by construction); entropy = log(l) - T/l, T = sum p*s.
// ---------------------------------------------------------------------------
__global__ __launch_bounds__(256, 2) void flash_attn(
    const unsigned short* __restrict__ Q,
    const unsigned short* __restrict__ K,
    const unsigned short* __restrict__ Vt,
    const int* __restrict__ mask,
    unsigned short* __restrict__ O,
    float* __restrict__ entp)
{
    const int qt = blockIdx.x;          // 0..15, 128 q-rows each
    const int bh = blockIdx.y;          // 0..31
    const int b = bh >> 4, h = bh & 15;
    const int t = threadIdx.x, lane = t & 63, w = t >> 6;
    const int quad = lane >> 4, l15 = lane & 15;
    const int r8 = lane >> 3, ch8 = lane & 7;   // staging row-in-8 / chunk

    __shared__ unsigned short Qs[128 * 72];      // Q staged once; reused as Ps
    __shared__ unsigned short Ks[2][64 * 64];    // [k-row][d], chunk swizzled by row&7
    __shared__ unsigned short Vs[2][64 * 64];    // [d-row][k], chunk swizzled by row&7

    // issue tile-0 K/V DMA (wave w stages rows w*16..w*16+15; 8 rows per glds16)
    {
        const int row0 = w * 16;
#pragma unroll
        for (int i = 0; i < 2; ++i) {
            int row = row0 + i * 8 + r8;
            int c = ch8 ^ (row & 7);           // global-side swizzle, same 128B lines
            glds16(&K[(size_t)(b * 2048 + row) * 1024 + h * 64 + c * 8], &Ks[0][(row0 + i * 8) * 64]);
            glds16(&Vt[(size_t)(h * 64 + row) * 4096 + b * 2048 + c * 8], &Vs[0][(row0 + i * 8) * 64]);
        }
    }
    // stage Q tile (once)
#pragma unroll
    for (int i = 0; i < 4; ++i) {
        int f = i * 256 + t; int row = f >> 3, c = f & 7;
        uint4 v = *(const uint4*)&Q[(size_t)(b * 2048 + qt * 128 + row) * 1024 + h * 64 + c * 8];
        *(uint4*)&Qs[row * 72 + c * 8] = v;
    }
    __syncthreads();   // Qs ready; tile-0 DMA drained (vmcnt0 in barrier)

    // hoist Q fragments; Qs LDS becomes Ps
    short8 qa[2][2];
#pragma unroll
    for (int st = 0; st < 2; ++st) {
        int qrow = w * 32 + st * 16 + l15;
        qa[st][0] = *(const short8*)&Qs[qrow * 72 + quad * 8];
        qa[st][1] = *(const short8*)&Qs[qrow * 72 + 32 + quad * 8];
    }
    unsigned short* Ps = Qs;

    float l_r[2][4], T_r[2][4];
    f32x4 o_acc[2][4];
#pragma unroll
    for (int st = 0; st < 2; ++st)
#pragma unroll
        for (int r = 0; r < 4; ++r) { l_r[st][r] = 0.f; T_r[st][r] = 0.f; }
#pragma unroll
    for (int st = 0; st < 2; ++st)
#pragma unroll
        for (int nt = 0; nt < 4; ++nt) o_acc[st][nt] = (f32x4){0.f, 0.f, 0.f, 0.f};

    const int* maskb = mask + b * 2048;

    for (int kt = 0; kt < 32; ++kt) {
        const int cur = kt & 1;
        // issue NEXT tile's DMA into the other buffer — overlaps this tile's compute
        if (kt < 31) {
            const int kn = (kt + 1) * 64;
            const int row0 = w * 16;
#pragma unroll
            for (int i = 0; i < 2; ++i) {
                int row = row0 + i * 8 + r8;
                int c = ch8 ^ (row & 7);
                glds16(&K[(size_t)(b * 2048 + kn + row) * 1024 + h * 64 + c * 8], &Ks[cur ^ 1][(row0 + i * 8) * 64]);
                glds16(&Vt[(size_t)(h * 64 + row) * 4096 + b * 2048 + kn + c * 8], &Vs[cur ^ 1][(row0 + i * 8) * 64]);
            }
        }

        // S = Q K^T : K frags shared across both q-subtiles
        f32x4 sacc[2][4];
#pragma unroll
        for (int st = 0; st < 2; ++st)
#pragma unroll
            for (int nt = 0; nt < 4; ++nt) sacc[st][nt] = (f32x4){0.f, 0.f, 0.f, 0.f};
#pragma unroll
        for (int nt = 0; nt < 4; ++nt) {
            int krow = nt * 16 + l15;
            short8 kf0 = *(const short8*)&Ks[cur][krow * 64 + ((quad ^ (krow & 7)) * 8)];
            short8 kf1 = *(const short8*)&Ks[cur][krow * 64 + (((quad + 4) ^ (krow & 7)) * 8)];
#pragma unroll
            for (int st = 0; st < 2; ++st) {
                sacc[st][nt] = __builtin_amdgcn_mfma_f32_16x16x32_bf16(qa[st][0], kf0, sacc[st][nt], 0, 0, 0);
                sacc[st][nt] = __builtin_amdgcn_mfma_f32_16x16x32_bf16(qa[st][1], kf1, sacc[st][nt], 0, 0, 0);
            }
        }
        int mk[4];
#pragma unroll
        for (int nt = 0; nt < 4; ++nt) mk[nt] = maskb[kt * 64 + nt * 16 + l15];

        // no-max softmax partials + P store (wave-local rows)
#pragma unroll
        for (int st = 0; st < 2; ++st) {
#pragma unroll
            for (int r = 0; r < 4; ++r) {
                float s0 = mk[0] ? sacc[st][0][r] : -1.0e30f;
                float s1 = mk[1] ? sacc[st][1][r] : -1.0e30f;
                float s2 = mk[2] ? sacc[st][2][r] : -1.0e30f;
                float s3 = mk[3] ? sacc[st][3][r] : -1.0e30f;
                float p0 = __expf(s0), p1 = __expf(s1), p2 = __expf(s2), p3 = __expf(s3);
                l_r[st][r] += (p0 + p1) + (p2 + p3);
                T_r[st][r] += (p0 * s0 + p1 * s1) + (p2 * s2 + p3 * s3);
                int pbase = (w * 32 + st * 16 + quad * 4 + r) * 72 + l15;
                Ps[pbase]      = f2bf(p0);
                Ps[pbase + 16] = f2bf(p1);
                Ps[pbase + 32] = f2bf(p2);
                Ps[pbase + 48] = f2bf(p3);
            }
        }

        // O += P V : V frags shared across both q-subtiles
#pragma unroll
        for (int ks = 0; ks < 2; ++ks) {
            short8 pa[2];
#pragma unroll
            for (int st = 0; st < 2; ++st)
                pa[st] = *(const short8*)&Ps[(w * 32 + st * 16 + l15) * 72 + ks * 32 + quad * 8];
#pragma unroll
            for (int nt = 0; nt < 4; ++nt) {
                int vrow = nt * 16 + l15;
                short8 vf = *(const short8*)&Vs[cur][vrow * 64 + ((((ks * 4 + quad)) ^ (vrow & 7)) * 8)];
#pragma unroll
                for (int st = 0; st < 2; ++st)
                    o_acc[st][nt] = __builtin_amdgcn_mfma_f32_16x16x32_bf16(pa[st], vf, o_acc[st][nt], 0, 0, 0);
            }
        }
        __syncthreads();  // all waves done reading buf[cur]; own next-tile DMA drained
    }

    // finalize: reduce l,T across 16 lanes per q-row; write O; entropy
    float entacc = 0.f;
#pragma unroll
    for (int st = 0; st < 2; ++st) {
#pragma unroll
        for (int r = 0; r < 4; ++r) {
            float l = l_r[st][r], T = T_r[st][r];
            l += __shfl_xor(l, 1); T += __shfl_xor(T, 1);
            l += __shfl_xor(l, 2); T += __shfl_xor(T, 2);
            l += __shfl_xor(l, 4); T += __shfl_xor(T, 4);
            l += __shfl_xor(l, 8); T += __shfl_xor(T, 8);
            float inv = 1.0f / l;
            float ent = __logf(l) - T * inv;   // -sum p log p
            if (l15 == 0) entacc += ent;
            int mrow = b * 2048 + qt * 128 + w * 32 + st * 16 + quad * 4 + r;
#pragma unroll
            for (int nt = 0; nt < 4; ++nt)
                O[(size_t)mrow * 1024 + h * 64 + nt * 16 + l15] = f2bf(o_acc[st][nt][r] * inv);
        }
    }
    entacc += __shfl_xor(entacc, 1);
    entacc += __shfl_xor(entacc, 2);
    entacc += __shfl_xor(entacc, 4);
    entacc += __shfl_xor(entacc, 8);
    entacc += __shfl_xor(entacc, 16);
    entacc += __shfl_xor(entacc, 32);
    if (lane == 0) atomicAdd(entp, entacc);
}

// ---------------------------------------------------------------------------
// Output GEMM bf16: out = scale_ent * (O @ ow.T) + ob, fp32 out. 128x64 tiles.
// ---------------------------------------------------------------------------
__global__ __launch_bounds__(256) void gemm_out_bf(
    const unsigned short* __restrict__ A, const unsigned short* __restrict__ Bw,
    const float* __restrict__ bias, const float* __restrict__ entp,
    float* __restrict__ C)
{
    const float avg = entp[0] * (1.0f / 65536.0f);
    const float scale = (avg < 0.2f) ? 1.0f : BLEND_C;

    const int m0 = blockIdx.x * 128;
    const int n0 = blockIdx.y * 64;
    __shared__ unsigned short As[128 * 32];
    __shared__ unsigned short Bs[64 * 32];
    const int t = threadIdx.x, lane = t & 63, w = t >> 6;
    const int quad = lane >> 4, l15 = lane & 15;
    const int wr = (w >> 1) * 64, wc = (w & 1) * 32;
    const int srow = lane >> 2, scol = (lane & 3) * 8;

    f32x4 acc[4][2];
#pragma unroll
    for (int i = 0; i < 4; ++i)
#pragma unroll
        for (int j = 0; j < 2; ++j) acc[i][j] = (f32x4){0.f, 0.f, 0.f, 0.f};

    for (int kk = 0; kk < 32; ++kk) {
        const int k0 = kk * 32;
#pragma unroll
        for (int j = 0; j < 2; ++j) {
            int row = (w * 2 + j) * 16 + srow;
            glds16(&A[(size_t)(m0 + row) * 1024 + k0 + scol], &As[(w * 2 + j) * 512]);
        }
        {
            int row = w * 16 + srow;
            glds16(&Bw[(size_t)(n0 + row) * 1024 + k0 + scol], &Bs[w * 512]);
        }
        __syncthreads();
        short8 af[4], bf[2];
#pragma unroll
        for (int mt = 0; mt < 4; ++mt) af[mt] = *(const short8*)&As[(wr + mt * 16 + l15) * 32 + quad * 8];
#pragma unroll
        for (int nt = 0; nt < 2; ++nt) bf[nt] = *(const short8*)&Bs[(wc + nt * 16 + l15) * 32 + quad * 8];
#pragma unroll
        for (int mt = 0; mt < 4; ++mt)
#pragma unroll
            for (int nt = 0; nt < 2; ++nt)
                acc[mt][nt] = __builtin_amdgcn_mfma_f32_16x16x32_bf16(af[mt], bf[nt], acc[mt][nt], 0, 0, 0);
        __syncthreads();
    }
#pragma unroll
    for (int mt = 0; mt < 4; ++mt) {
#pragma unroll
        for (int nt = 0; nt < 2; ++nt) {
            int n = n0 + wc + nt * 16 + l15;
#pragma unroll
            for (int r = 0; r < 4; ++r) {
                int m = m0 + wr + mt * 16 + quad * 4 + r;
                C[(size_t)m * 1024 + n] = scale * acc[mt][nt][r] + bias[n];
            }
        }
    }
}

// ---------------------------------------------------------------------------
// Fallback kernels (round-2 proven): fp32-staged GEMMs.
// ---------------------------------------------------------------------------
__global__ __launch_bounds__(256) void gemm_nt_f32(
    const float* __restrict__ A, const float* __restrict__ B,
    const float* __restrict__ bias, int biasRow, float scale,
    unsigned short* __restrict__ C, int N)
{
    const int m0 = blockIdx.x * 128;
    const int n0 = blockIdx.y * 128;
    __shared__ unsigned short As[128 * 40];
    __shared__ unsigned short Bs[128 * 40];
    const int t = threadIdx.x, lane = t & 63, w = t >> 6;
    const int wr = (w >> 1) * 64, wc = (w & 1) * 64;
    const int quad = lane >> 4, l15 = lane & 15;

    f32x4 acc[4][4];
#pragma unroll
    for (int i = 0; i < 4; ++i)
#pragma unroll
        for (int j = 0; j < 4; ++j) acc[i][j] = (f32x4){0.f, 0.f, 0.f, 0.f};

    for (int kk = 0; kk < 32; ++kk) {
        const int k0 = kk * 32;
#pragma unroll
        for (int i = 0; i < 4; ++i) {
            int f = i * 256 + t;
            int row = f >> 3, ch = f & 7;
            float4 av = *(const float4*)&A[(size_t)(m0 + row) * 1024 + k0 + ch * 4];
            ushort4 ap; ap.x = f2bf(av.x); ap.y = f2bf(av.y); ap.z = f2bf(av.z); ap.w = f2bf(av.w);
            *(ushort4*)&As[row * 40 + ch * 4] = ap;
            float4 bv = *(const float4*)&B[(size_t)(n0 + row) * 1024 + k0 + ch * 4];
            ushort4 bp; bp.x = f2bf(bv.x); bp.y = f2bf(bv.y); bp.z = f2bf(bv.z); bp.w = f2bf(bv.w);
            *(ushort4*)&Bs[row * 40 + ch * 4] = bp;
        }
        __syncthreads();
        short8 af[4], bfr[4];
#pragma unroll
        for (int mt = 0; mt < 4; ++mt) af[mt] = *(const short8*)&As[(wr + mt * 16 + l15) * 40 + quad * 8];
#pragma unroll
        for (int nt = 0; nt < 4; ++nt) bfr[nt] = *(const short8*)&Bs[(wc + nt * 16 + l15) * 40 + quad * 8];
#pragma unroll
        for (int mt = 0; mt < 4; ++mt)
#pragma unroll
            for (int nt = 0; nt < 4; ++nt)
                acc[mt][nt] = __builtin_amdgcn_mfma_f32_16x16x32_bf16(af[mt], bfr[nt], acc[mt][nt], 0, 0, 0);
        __syncthreads();
    }
#pragma unroll
    for (int mt = 0; mt < 4; ++mt) {
#pragma unroll
        for (int nt = 0; nt < 4; ++nt) {
            int n = n0 + wc + nt * 16 + l15;
#pragma unroll
            for (int r = 0; r < 4; ++r) {
                int m = m0 + wr + mt * 16 + quad * 4 + r;
                float bval = biasRow ? bias[m] : bias[n];
                C[(size_t)m * N + n] = f2bf((acc[mt][nt][r] + bval) * scale);
            }
        }
    }
}

__global__ __launch_bounds__(256) void gemm_out_f32B(
    const unsigned short* __restrict__ A, const float* __restrict__ B,
    const float* __restrict__ bias, const float* __restrict__ entp,
    float* __restrict__ C)
{
    const float avg = entp[0] * (1.0f / 65536.0f);
    const float scale = (avg < 0.2f) ? 1.0f : BLEND_C;

    const int m0 = blockIdx.x * 128;
    const int n0 = blockIdx.y * 128;
    __shared__ unsigned short As[128 * 40];
    __shared__ unsigned short Bs[128 * 40];
    const int t = threadIdx.x, lane = t & 63, w = t >> 6;
    const int wr = (w >> 1) * 64, wc = (w & 1) * 64;
    const int quad = lane >> 4, l15 = lane & 15;

    f32x4 acc[4][4];
#pragma unroll
    for (int i = 0; i < 4; ++i)
#pragma unroll
        for (int j = 0; j < 4; ++j) acc[i][j] = (f32x4){0.f, 0.f, 0.f, 0.f};

    for (int kk = 0; kk < 32; ++kk) {
        const int k0 = kk * 32;
#pragma unroll
        for (int i = 0; i < 2; ++i) {
            int f = i * 256 + t;
            int row = f >> 2, ch = f & 3;
            uint4 av = *(const uint4*)&A[(size_t)(m0 + row) * 1024 + k0 + ch * 8];
            *(uint4*)&As[row * 40 + ch * 8] = av;
        }
#pragma unroll
        for (int i = 0; i < 4; ++i) {
            int f = i * 256 + t;
            int row = f >> 3, ch = f & 7;
            float4 bv = *(const float4*)&B[(size_t)(n0 + row) * 1024 + k0 + ch * 4];
            ushort4 bp; bp.x = f2bf(bv.x); bp.y = f2bf(bv.y); bp.z = f2bf(bv.z); bp.w = f2bf(bv.w);
            *(ushort4*)&Bs[row * 40 + ch * 4] = bp;
        }
        __syncthreads();
        short8 af[4], bfr[4];
#pragma unroll
        for (int mt = 0; mt < 4; ++mt) af[mt] = *(const short8*)&As[(wr + mt * 16 + l15) * 40 + quad * 8];
#pragma unroll
        for (int nt = 0; nt < 4; ++nt) bfr[nt] = *(const short8*)&Bs[(wc + nt * 16 + l15) * 40 + quad * 8];
#pragma unroll
        for (int mt = 0; mt < 4; ++mt)
#pragma unroll
            for (int nt = 0; nt < 4; ++nt)
                acc[mt][nt] = __builtin_amdgcn_mfma_f32_16x16x32_bf16(af[mt], bfr[nt], acc[mt][nt], 0, 0, 0);
        __syncthreads();
    }
#pragma unroll
    for (int mt = 0; mt < 4; ++mt) {
#pragma unroll
        for (int nt = 0; nt < 4; ++nt) {
            int n = n0 + wc + nt * 16 + l15;
#pragma unroll
            for (int r = 0; r < 4; ++r) {
                int m = m0 + wr + mt * 16 + quad * 4 + r;
                C[(size_t)m * 1024 + n] = scale * acc[mt][nt][r] + bias[n];
            }
        }
    }
}

extern "C" void kernel_launch(void* const* d_in, const int* in_sizes, int n_in,
                              void* d_out, int out_size, void* d_ws, size_t ws_size,
                              hipStream_t stream)
{
    const float* hs = (const float*)d_in[0];
    const float* qw = (const float*)d_in[1];
    const float* qb = (const float*)d_in[2];
    const float* kw = (const float*)d_in[3];
    const float* kb = (const float*)d_in[4];
    const float* vw = (const float*)d_in[5];
    const float* vb = (const float*)d_in[6];
    const float* ow = (const float*)d_in[7];
    const float* ob = (const float*)d_in[8];
    const int*   mask = (const int*)d_in[9];
    float* out = (float*)d_out;

    const size_t MB = 1024 * 1024;
    char* ws = (char*)d_ws;
    dim3 blk(256);

    if (ws_size >= 40 * MB + 4) {
        // primary path
        unsigned short* hsb = (unsigned short*)(ws);            // 8MB; reused as O by flash
        unsigned short* Q   = (unsigned short*)(ws + 8 * MB);
        unsigned short* Kp  = (unsigned short*)(ws + 16 * MB);
        unsigned short* Vt  = (unsigned short*)(ws + 24 * MB);
        unsigned short* qwb = (unsigned short*)(ws + 32 * MB);
        unsigned short* kwb = (unsigned short*)(ws + 34 * MB);
        unsigned short* vwb = (unsigned short*)(ws + 36 * MB);
        unsigned short* owb = (unsigned short*)(ws + 38 * MB);
        float* entp         = (float*)(ws + 40 * MB);
        unsigned short* O   = hsb;  // hs_bf dead after gemm_qkv

        cvt5<<<dim3(8192), blk, 0, stream>>>(hs, qw, kw, vw, ow, hsb, qwb, kwb, vwb, owb, entp);
        gemm_qkv<<<dim3(768), blk, 0, stream>>>(hsb, qwb, kwb, vwb, qb, kb, vb, Q, Kp, Vt);
        flash_attn<<<dim3(16, 32), blk, 0, stream>>>(Q, Kp, Vt, mask, O, entp);
        gemm_out_bf<<<dim3(32, 16), blk, 0, stream>>>(O, owb, ob, entp, out);
    } else if (ws_size >= 32 * MB + 4) {
        // fallback: round-2 proven GEMMs + new flash
        unsigned short* Q  = (unsigned short*)(ws);
        unsigned short* Kp = (unsigned short*)(ws + 8 * MB);
        unsigned short* Vt = (unsigned short*)(ws + 16 * MB);
        unsigned short* O  = (unsigned short*)(ws + 24 * MB);
        float* entp        = (float*)(ws + 32 * MB);

        zero_ent<<<dim3(1), dim3(1), 0, stream>>>(entp);
        gemm_nt_f32<<<dim3(32, 8), blk, 0, stream>>>(hs, qw, qb, 0, PRIME_SCALE, Q, 1024);
        gemm_nt_f32<<<dim3(32, 8), blk, 0, stream>>>(hs, kw, kb, 0, 1.0f, Kp, 1024);
        gemm_nt_f32<<<dim3(8, 32), blk, 0, stream>>>(vw, hs, vb, 1, 1.0f, Vt, 4096);
        flash_attn<<<dim3(16, 32), blk, 0, stream>>>(Q, Kp, Vt, mask, O, entp);
        gemm_out_f32B<<<dim3(32, 8), blk, 0, stream>>>(O, ow, ob, entp, out);
    } else {
        // diagnostic: clean zero output instead of OOB fault
        zero_out_f32<<<dim3((out_size + 255) / 256), blk, 0, stream>>>(out, out_size);
    }
}